// Round 7
// baseline (190.756 us; speedup 1.0000x reference)
//
#include <hip/hip_runtime.h>
#include <hip/hip_bf16.h>
#include <stdint.h>

typedef __attribute__((ext_vector_type(4))) float f32x4;
typedef __attribute__((ext_vector_type(8))) short bf16x8;
typedef __attribute__((ext_vector_type(4))) int i32x4;

constexpr int SDIM = 2048;
constexpr int ODIM = 4096;
constexpr int INTD = 3840;
constexpr int FPD  = 256;

// RNE float->bf16
__device__ __forceinline__ unsigned short f2bf(float f) {
  union { float f; unsigned u; } a; a.f = f;
  unsigned r = a.u + 0x7fffu + ((a.u >> 16) & 1u);
  return (unsigned short)(r >> 16);
}

__device__ __forceinline__ void gload16(const void* g, void* l) {
  __builtin_amdgcn_global_load_lds(
      (const __attribute__((address_space(1))) void*)g,
      (__attribute__((address_space(3))) void*)l, 16, 0, 0);
}

// ---------------------------------------------------------------------------
// Fused prep (unchanged from round 5): blocks [0,2048) -> x rows,
// [2048,6144) -> weight rows.
// ---------------------------------------------------------------------------
__global__ __launch_bounds__(256) void prep_kernel(
    const float* __restrict__ x,
    const float* __restrict__ iw,
    const float* __restrict__ fw,
    const int* __restrict__ int_idx,
    const int* __restrict__ fp_idx,
    unsigned* __restrict__ A8,
    unsigned short* __restrict__ Afp,
    unsigned* __restrict__ W8,
    unsigned short* __restrict__ Wfp,
    float* __restrict__ qs)
{
  const int t = threadIdx.x;
  if (blockIdx.x >= SDIM) {
    const int o = blockIdx.x - SDIM;
    const float* iwr = iw + (size_t)o * INTD;
    unsigned* Wr = W8 + (size_t)o * 960;
    #pragma unroll
    for (int i = 0; i < 4; ++i) {
      const int g = t + (i << 8);
      if (g < 960) {
        float4 v = ((const float4*)iwr)[g];
        int q0 = __float2int_rn(v.x), q1 = __float2int_rn(v.y);
        int q2 = __float2int_rn(v.z), q3 = __float2int_rn(v.w);
        Wr[g] = (unsigned)(q0 & 255) | ((unsigned)(q1 & 255) << 8) |
                ((unsigned)(q2 & 255) << 16) | ((unsigned)(q3 & 255) << 24);
      }
    }
    Wfp[(size_t)o * FPD + t] = f2bf(fw[(size_t)o * FPD + t]);
    return;
  }

  __shared__ float row[4096];
  __shared__ float red[4];
  const int s = blockIdx.x;
  const float* xr = x + (size_t)s * 4096;
  #pragma unroll
  for (int i = 0; i < 4; ++i)
    ((float4*)row)[t + 256 * i] = ((const float4*)xr)[t + 256 * i];
  __syncthreads();

  float vals[16];
  float m = 0.f;
  #pragma unroll
  for (int i = 0; i < 4; ++i) {
    const int g = t + (i << 8);
    if (g < 960) {
      int4 idx = ((const int4*)int_idx)[g];
      float v0 = row[idx.x], v1 = row[idx.y], v2 = row[idx.z], v3 = row[idx.w];
      vals[i*4+0] = v0; vals[i*4+1] = v1; vals[i*4+2] = v2; vals[i*4+3] = v3;
      m = fmaxf(m, fmaxf(fmaxf(fabsf(v0), fabsf(v1)), fmaxf(fabsf(v2), fabsf(v3))));
    }
  }
  #pragma unroll
  for (int off = 32; off; off >>= 1)
    m = fmaxf(m, __shfl_xor(m, off));
  if ((t & 63) == 0) red[t >> 6] = m;
  __syncthreads();
  const float mx = fmaxf(fmaxf(red[0], red[1]), fmaxf(red[2], red[3]));
  if (t == 0) qs[s] = mx / 127.0f;
  const float rcp = 127.0f / mx;

  unsigned* Ar = A8 + (size_t)s * 960;
  #pragma unroll
  for (int i = 0; i < 4; ++i) {
    const int g = t + (i << 8);
    if (g < 960) {
      unsigned pk = 0;
      #pragma unroll
      for (int e = 0; e < 4; ++e) {
        float q = rintf(vals[i*4+e] * rcp);
        q = fminf(fmaxf(q, -128.f), 127.f);
        pk |= ((unsigned)((int)q & 255)) << (e * 8);
      }
      Ar[g] = pk;
    }
  }
  Afp[(size_t)s * FPD + t] = f2bf(row[fp_idx[t]]);
}

// ---------------------------------------------------------------------------
// GEMM v2: T3+T4+T5 schedule. BM=128 BN=256 BK=128B, 8 waves (2Mx4N),
// triple-buffered LDS, depth-2 prefetch, counted vmcnt(6), raw barriers,
// setprio around MFMA. 34 unified K-tiles: 0..29 i8, 30..33 bf16 (fp part).
// ---------------------------------------------------------------------------
__global__ __launch_bounds__(512, 2) void gemm_kernel(
    const char* __restrict__ A8,    // SDIM x 3840 (i8)
    const char* __restrict__ W8,    // ODIM x 3840 (i8)
    const char* __restrict__ Afp,   // SDIM x 512 B (bf16)
    const char* __restrict__ Wfp,   // ODIM x 512 B (bf16)
    const float* __restrict__ qs,
    const float* __restrict__ wsc,
    const float* __restrict__ bias,
    float* __restrict__ out)        // SDIM x ODIM f32
{
  __shared__ char ldsA[3][128 * 128];   // 48 KiB
  __shared__ char ldsB[3][256 * 128];   // 96 KiB
  const int tid  = threadIdx.x;
  const int lane = tid & 63;
  const int wid  = tid >> 6;            // 0..7
  const int wr   = wid >> 2;            // 0..1 (M)
  const int wc   = wid & 3;             // 0..3 (N)

  const int bid = blockIdx.x;           // 256 blocks; 256%8==0 -> bijective
  const int swz = (bid & 7) * 32 + (bid >> 3);
  const int srow0 = (swz & 15) * 128;
  const int ocol0 = (swz >> 4) * 256;

  const int r4 = (lane >> 4) * 4;
  const int cn = lane & 15;

  // Hoist scale loads BEFORE any staging so no vmem op pollutes vmcnt counts.
  float wo[4], qv[4][4];
  #pragma unroll
  for (int j = 0; j < 4; ++j) wo[j] = wsc[ocol0 + wc * 64 + j * 16 + cn];
  #pragma unroll
  for (int i = 0; i < 4; ++i)
    #pragma unroll
    for (int r = 0; r < 4; ++r)
      qv[i][r] = qs[srow0 + wr * 64 + i * 16 + r4 + r];

  // Swizzled read offsets: logical chunk c -> physical c ^ (row&7).
  int aoff[2][4], boff[2][4];
  #pragma unroll
  for (int kk = 0; kk < 2; ++kk) {
    #pragma unroll
    for (int i = 0; i < 4; ++i) {
      const int rowA = wr * 64 + i * 16 + (lane & 15);
      const int rowB = wc * 64 + i * 16 + (lane & 15);
      const int c    = kk * 4 + (lane >> 4);
      aoff[kk][i] = rowA * 128 + ((c ^ (rowA & 7)) * 16);
      boff[kk][i] = rowB * 128 + ((c ^ (rowB & 7)) * 16);
    }
  }

  // Staging: wave-uniform LDS base + lane*16 (gload_lds constraint, m104).
  // Pre-swizzle the GLOBAL source chunk so read-side XOR un-swizzles (rule #21).
  auto stageA = [&](int tt, int buf) {        // 2 loads/thread
    const bool f = (tt >= 30);
    const char* As = f ? Afp : A8;
    const size_t st = f ? 512 : (size_t)INTD;
    const int ko = f ? (tt - 30) * 128 : tt * 128;
    #pragma unroll
    for (int q = 0; q < 2; ++q) {
      const int rb = wid * 16 + q * 8;
      const int rl = rb + (lane >> 3);
      const int cl = (lane & 7) ^ (rl & 7);
      gload16(As + (size_t)(srow0 + rl) * st + ko + cl * 16,
              &ldsA[buf][rb * 128]);
    }
  };
  auto stageB = [&](int tt, int buf) {        // 4 loads/thread
    const bool f = (tt >= 30);
    const char* Bs = f ? Wfp : W8;
    const size_t st = f ? 512 : (size_t)INTD;
    const int ko = f ? (tt - 30) * 128 : tt * 128;
    #pragma unroll
    for (int q = 0; q < 4; ++q) {
      const int rb = wid * 32 + q * 8;
      const int rl = rb + (lane >> 3);
      const int cl = (lane & 7) ^ (rl & 7);
      gload16(Bs + (size_t)(ocol0 + rl) * st + ko + cl * 16,
              &ldsB[buf][rb * 128]);
    }
  };

  i32x4 iacc[4][4];
  #pragma unroll
  for (int i = 0; i < 4; ++i)
    #pragma unroll
    for (int j = 0; j < 4; ++j)
      iacc[i][j] = i32x4{0, 0, 0, 0};

  // Prologue: tiles 0 and 1 in flight; wait for tile 0 only (6 newest stay out).
  stageA(0, 0); stageB(0, 0);
  stageA(1, 1); stageB(1, 1);
  asm volatile("s_waitcnt vmcnt(6)" ::: "memory");
  __builtin_amdgcn_s_barrier();

  int buf = 0;
  // ---- i8 main loop: tiles 0..29 ----
  for (int t = 0; t < 30; ++t) {
    const int nb = (buf >= 1) ? buf - 1 : buf + 2;   // (buf+2)%3
    // phase kk=0
    {
      i32x4 af[4], bv[4];
      #pragma unroll
      for (int i = 0; i < 4; ++i) af[i] = *(const i32x4*)(ldsA[buf] + aoff[0][i]);
      #pragma unroll
      for (int j = 0; j < 4; ++j) bv[j] = *(const i32x4*)(ldsB[buf] + boff[0][j]);
      if (t + 2 < 34) stageA(t + 2, nb);
      __builtin_amdgcn_s_barrier();
      asm volatile("s_waitcnt lgkmcnt(0)" ::: "memory");
      __builtin_amdgcn_sched_barrier(0);
      __builtin_amdgcn_s_setprio(1);
      #pragma unroll
      for (int i = 0; i < 4; ++i)
        #pragma unroll
        for (int j = 0; j < 4; ++j)
          iacc[i][j] = __builtin_amdgcn_mfma_i32_16x16x64_i8(
              af[i], bv[j], iacc[i][j], 0, 0, 0);
      __builtin_amdgcn_s_setprio(0);
      __builtin_amdgcn_sched_barrier(0);
      __builtin_amdgcn_s_barrier();
    }
    // phase kk=1
    {
      i32x4 af[4], bv[4];
      #pragma unroll
      for (int i = 0; i < 4; ++i) af[i] = *(const i32x4*)(ldsA[buf] + aoff[1][i]);
      #pragma unroll
      for (int j = 0; j < 4; ++j) bv[j] = *(const i32x4*)(ldsB[buf] + boff[1][j]);
      if (t + 2 < 34) stageB(t + 2, nb);
      __builtin_amdgcn_s_barrier();
      asm volatile("s_waitcnt lgkmcnt(0)" ::: "memory");
      __builtin_amdgcn_sched_barrier(0);
      __builtin_amdgcn_s_setprio(1);
      #pragma unroll
      for (int i = 0; i < 4; ++i)
        #pragma unroll
        for (int j = 0; j < 4; ++j)
          iacc[i][j] = __builtin_amdgcn_mfma_i32_16x16x64_i8(
              af[i], bv[j], iacc[i][j], 0, 0, 0);
      __builtin_amdgcn_s_setprio(0);
      __builtin_amdgcn_sched_barrier(0);
      // counted drain: tile t+1 must be landed; t+2's 6 loads stay in flight
      if (t + 2 < 34) asm volatile("s_waitcnt vmcnt(6)" ::: "memory");
      else            asm volatile("s_waitcnt vmcnt(0)" ::: "memory");
      __builtin_amdgcn_s_barrier();
    }
    buf = (buf == 2) ? 0 : buf + 1;
  }

  // Convert i32 acc -> f32 with per-row/col scales (pure VALU, between loops).
  f32x4 facc[4][4];
  #pragma unroll
  for (int i = 0; i < 4; ++i)
    #pragma unroll
    for (int j = 0; j < 4; ++j)
      #pragma unroll
      for (int r = 0; r < 4; ++r)
        facc[i][j][r] = (float)iacc[i][j][r] * wo[j] * qv[i][r];

  // ---- bf16 fp tail: tiles 30..33, same pipeline ----
  for (int t = 30; t < 34; ++t) {
    const int nb = (buf >= 1) ? buf - 1 : buf + 2;
    {
      bf16x8 af[4], bv[4];
      #pragma unroll
      for (int i = 0; i < 4; ++i) af[i] = *(const bf16x8*)(ldsA[buf] + aoff[0][i]);
      #pragma unroll
      for (int j = 0; j < 4; ++j) bv[j] = *(const bf16x8*)(ldsB[buf] + boff[0][j]);
      if (t + 2 < 34) stageA(t + 2, nb);
      __builtin_amdgcn_s_barrier();
      asm volatile("s_waitcnt lgkmcnt(0)" ::: "memory");
      __builtin_amdgcn_sched_barrier(0);
      __builtin_amdgcn_s_setprio(1);
      #pragma unroll
      for (int i = 0; i < 4; ++i)
        #pragma unroll
        for (int j = 0; j < 4; ++j)
          facc[i][j] = __builtin_amdgcn_mfma_f32_16x16x32_bf16(
              af[i], bv[j], facc[i][j], 0, 0, 0);
      __builtin_amdgcn_s_setprio(0);
      __builtin_amdgcn_sched_barrier(0);
      __builtin_amdgcn_s_barrier();
    }
    {
      bf16x8 af[4], bv[4];
      #pragma unroll
      for (int i = 0; i < 4; ++i) af[i] = *(const bf16x8*)(ldsA[buf] + aoff[1][i]);
      #pragma unroll
      for (int j = 0; j < 4; ++j) bv[j] = *(const bf16x8*)(ldsB[buf] + boff[1][j]);
      if (t + 2 < 34) stageB(t + 2, nb);
      __builtin_amdgcn_s_barrier();
      asm volatile("s_waitcnt lgkmcnt(0)" ::: "memory");
      __builtin_amdgcn_sched_barrier(0);
      __builtin_amdgcn_s_setprio(1);
      #pragma unroll
      for (int i = 0; i < 4; ++i)
        #pragma unroll
        for (int j = 0; j < 4; ++j)
          facc[i][j] = __builtin_amdgcn_mfma_f32_16x16x32_bf16(
              af[i], bv[j], facc[i][j], 0, 0, 0);
      __builtin_amdgcn_s_setprio(0);
      __builtin_amdgcn_sched_barrier(0);
      if (t + 2 < 34)      asm volatile("s_waitcnt vmcnt(6)" ::: "memory");
      else if (t + 2 == 34) asm volatile("s_waitcnt vmcnt(0)" ::: "memory");
      __builtin_amdgcn_s_barrier();
    }
    buf = (buf == 2) ? 0 : buf + 1;
  }

  // Epilogue: C/D layout col=lane&15, row=(lane>>4)*4+reg.
  #pragma unroll
  for (int j = 0; j < 4; ++j) {
    const int o  = ocol0 + wc * 64 + j * 16 + cn;
    const float bo = bias[o];
    #pragma unroll
    for (int i = 0; i < 4; ++i) {
      const int sbase = srow0 + wr * 64 + i * 16 + r4;
      #pragma unroll
      for (int r = 0; r < 4; ++r)
        out[(size_t)(sbase + r) * ODIM + o] = facc[i][j][r] + bo;
    }
  }
}

// ---------------------------------------------------------------------------
extern "C" void kernel_launch(void* const* d_in, const int* in_sizes, int n_in,
                              void* d_out, int out_size, void* d_ws, size_t ws_size,
                              hipStream_t stream) {
  const float* x    = (const float*)d_in[0];
  const float* iw   = (const float*)d_in[1];
  const float* fw   = (const float*)d_in[2];
  const float* wsc  = (const float*)d_in[3];
  const float* bias = (const float*)d_in[4];
  const int* int_idx = (const int*)d_in[5];
  const int* fp_idx  = (const int*)d_in[6];
  float* out = (float*)d_out;

  char* ws = (char*)d_ws;
  char* A8  = ws;                                   // 2048*3840  = 7.86 MB
  char* W8  = A8 + (size_t)SDIM * INTD;             // 4096*3840  = 15.7 MB
  char* Afp = W8 + (size_t)ODIM * INTD;             // 2048*256*2 = 1.0 MB
  char* Wfp = Afp + (size_t)SDIM * FPD * 2;         // 4096*256*2 = 2.1 MB
  float* qs = (float*)(Wfp + (size_t)ODIM * FPD * 2);

  prep_kernel<<<SDIM + ODIM, 256, 0, stream>>>(x, iw, fw, int_idx, fp_idx,
                                               (unsigned*)A8, (unsigned short*)Afp,
                                               (unsigned*)W8, (unsigned short*)Wfp, qs);
  gemm_kernel<<<256, 512, 0, stream>>>(A8, W8, Afp, Wfp, qs, wsc, bias, out);
}

// Round 8
// 179.259 us; speedup vs baseline: 1.0641x; 1.0641x over previous
//
#include <hip/hip_runtime.h>
#include <hip/hip_bf16.h>
#include <stdint.h>

typedef __attribute__((ext_vector_type(4))) float f32x4;
typedef __attribute__((ext_vector_type(8))) short bf16x8;
typedef __attribute__((ext_vector_type(4))) int i32x4;

constexpr int SDIM = 2048;
constexpr int ODIM = 4096;
constexpr int INTD = 3840;
constexpr int FPD  = 256;

// RNE float->bf16
__device__ __forceinline__ unsigned short f2bf(float f) {
  union { float f; unsigned u; } a; a.f = f;
  unsigned r = a.u + 0x7fffu + ((a.u >> 16) & 1u);
  return (unsigned short)(r >> 16);
}

__device__ __forceinline__ void gload16(const void* g, void* l) {
  __builtin_amdgcn_global_load_lds(
      (const __attribute__((address_space(1))) void*)g,
      (__attribute__((address_space(3))) void*)l, 16, 0, 0);
}

// ---------------------------------------------------------------------------
// Fused prep: blocks [0,2048) -> x rows, [2048,6144) -> weight rows.
// Read-once inputs (x, iw, fw) use NON-TEMPORAL loads so they don't evict
// the freshly-written A8/W8/Afp/Wfp from L2 (the gemm reads those next).
// ---------------------------------------------------------------------------
__global__ __launch_bounds__(256) void prep_kernel(
    const float* __restrict__ x,
    const float* __restrict__ iw,
    const float* __restrict__ fw,
    const int* __restrict__ int_idx,
    const int* __restrict__ fp_idx,
    unsigned* __restrict__ A8,
    unsigned short* __restrict__ Afp,
    unsigned* __restrict__ W8,
    unsigned short* __restrict__ Wfp,
    float* __restrict__ qs)
{
  const int t = threadIdx.x;
  if (blockIdx.x >= SDIM) {
    const int o = blockIdx.x - SDIM;
    const f32x4* iwr = (const f32x4*)(iw + (size_t)o * INTD);
    unsigned* Wr = W8 + (size_t)o * 960;
    #pragma unroll
    for (int i = 0; i < 4; ++i) {
      const int g = t + (i << 8);
      if (g < 960) {
        f32x4 v = __builtin_nontemporal_load(iwr + g);   // read-once: bypass-ish
        int q0 = __float2int_rn(v[0]), q1 = __float2int_rn(v[1]);
        int q2 = __float2int_rn(v[2]), q3 = __float2int_rn(v[3]);
        Wr[g] = (unsigned)(q0 & 255) | ((unsigned)(q1 & 255) << 8) |
                ((unsigned)(q2 & 255) << 16) | ((unsigned)(q3 & 255) << 24);
      }
    }
    const float fwv = __builtin_nontemporal_load(fw + (size_t)o * FPD + t);
    Wfp[(size_t)o * FPD + t] = f2bf(fwv);
    return;
  }

  __shared__ float row[4096];
  __shared__ float red[4];
  const int s = blockIdx.x;
  const f32x4* xr = (const f32x4*)(x + (size_t)s * 4096);
  #pragma unroll
  for (int i = 0; i < 4; ++i)
    ((f32x4*)row)[t + 256 * i] = __builtin_nontemporal_load(xr + t + 256 * i);
  __syncthreads();

  float vals[16];
  float m = 0.f;
  #pragma unroll
  for (int i = 0; i < 4; ++i) {
    const int g = t + (i << 8);
    if (g < 960) {
      int4 idx = ((const int4*)int_idx)[g];
      float v0 = row[idx.x], v1 = row[idx.y], v2 = row[idx.z], v3 = row[idx.w];
      vals[i*4+0] = v0; vals[i*4+1] = v1; vals[i*4+2] = v2; vals[i*4+3] = v3;
      m = fmaxf(m, fmaxf(fmaxf(fabsf(v0), fabsf(v1)), fmaxf(fabsf(v2), fabsf(v3))));
    }
  }
  #pragma unroll
  for (int off = 32; off; off >>= 1)
    m = fmaxf(m, __shfl_xor(m, off));
  if ((t & 63) == 0) red[t >> 6] = m;
  __syncthreads();
  const float mx = fmaxf(fmaxf(red[0], red[1]), fmaxf(red[2], red[3]));
  if (t == 0) qs[s] = mx / 127.0f;        // exactly as reference: max/QMAX
  const float rcp = 127.0f / mx;

  unsigned* Ar = A8 + (size_t)s * 960;
  #pragma unroll
  for (int i = 0; i < 4; ++i) {
    const int g = t + (i << 8);
    if (g < 960) {
      unsigned pk = 0;
      #pragma unroll
      for (int e = 0; e < 4; ++e) {
        float q = rintf(vals[i*4+e] * rcp);
        q = fminf(fmaxf(q, -128.f), 127.f);
        pk |= ((unsigned)((int)q & 255)) << (e * 8);
      }
      Ar[g] = pk;
    }
  }
  Afp[(size_t)s * FPD + t] = f2bf(row[fp_idx[t]]);
}

// ---------------------------------------------------------------------------
// GEMM (reverted to the r3/r5-validated 2-phase structure):
// fused i8 (K=3840) + bf16 (K=256), 128x128 tile, 4 waves, 2 blocks/CU,
// double-buffered LDS, gload_lds w=16, XOR chunk swizzle both-sides.
// out[s,o] = (i8dot)*wsc[o]*qs[s] + (fp dot) + bias[o]
// ---------------------------------------------------------------------------
__global__ __launch_bounds__(256, 2) void gemm_kernel(
    const char* __restrict__ A8,    // SDIM x 3840 (i8)
    const char* __restrict__ W8,    // ODIM x 3840 (i8)
    const char* __restrict__ Afp,   // SDIM x 512 B (bf16)
    const char* __restrict__ Wfp,   // ODIM x 512 B (bf16)
    const float* __restrict__ qs,
    const float* __restrict__ wsc,
    const float* __restrict__ bias,
    float* __restrict__ out)        // SDIM x ODIM f32
{
  __shared__ char lds[2][2][128][128];   // 64 KiB
  const int tid  = threadIdx.x;
  const int lane = tid & 63;
  const int wid  = tid >> 6;
  const int wr   = wid >> 1, wc = wid & 1;

  const int bid = blockIdx.x;
  const int swz = (bid & 7) * 64 + (bid >> 3);   // 512 % 8 == 0 -> bijective
  const int bm  = swz & 15;
  const int bn  = swz >> 4;
  const int srow0 = bm * 128;
  const int ocol0 = bn * 128;

  int aoff[2][4], boff[2][4];
  #pragma unroll
  for (int kk = 0; kk < 2; ++kk) {
    #pragma unroll
    for (int i = 0; i < 4; ++i) {
      const int rowA = wr * 64 + i * 16 + (lane & 15);
      const int rowB = wc * 64 + i * 16 + (lane & 15);
      const int c    = kk * 4 + (lane >> 4);
      aoff[kk][i] = rowA * 128 + ((c ^ (rowA & 7)) * 16);
      boff[kk][i] = rowB * 128 + ((c ^ (rowB & 7)) * 16);
    }
  }

  const int rloc0 = wid * 32 + (lane >> 3);
  const int clA   = (lane & 7);

  auto stage8 = [&](int ktB, int buf) {
    #pragma unroll
    for (int q = 0; q < 4; ++q) {
      const int rl = rloc0 + q * 8;
      const int cl = clA ^ (rl & 7);
      gload16(A8 + (size_t)(srow0 + rl) * INTD + ktB + cl * 16,
              &lds[buf][0][wid * 32 + q * 8][0]);
      gload16(W8 + (size_t)(ocol0 + rl) * INTD + ktB + cl * 16,
              &lds[buf][1][wid * 32 + q * 8][0]);
    }
  };
  auto stagefp = [&](int ktB, int buf) {
    #pragma unroll
    for (int q = 0; q < 4; ++q) {
      const int rl = rloc0 + q * 8;
      const int cl = clA ^ (rl & 7);
      gload16(Afp + (size_t)(srow0 + rl) * 512 + ktB + cl * 16,
              &lds[buf][0][wid * 32 + q * 8][0]);
      gload16(Wfp + (size_t)(ocol0 + rl) * 512 + ktB + cl * 16,
              &lds[buf][1][wid * 32 + q * 8][0]);
    }
  };

  i32x4 iacc[4][4];
  #pragma unroll
  for (int i = 0; i < 4; ++i)
    #pragma unroll
    for (int j = 0; j < 4; ++j)
      iacc[i][j] = i32x4{0, 0, 0, 0};

  stage8(0, 0);
  int cur = 0;
  constexpr int NT8 = INTD / 128;   // 30
  for (int t = 0; t < NT8; ++t) {
    __syncthreads();
    if (t + 1 < NT8) stage8((t + 1) * 128, cur ^ 1);
    else             stagefp(0, cur ^ 1);
    const char* Al = &lds[cur][0][0][0];
    const char* Bl = &lds[cur][1][0][0];
    #pragma unroll
    for (int kk = 0; kk < 2; ++kk) {
      i32x4 af[4], bv[4];
      #pragma unroll
      for (int i = 0; i < 4; ++i) af[i] = *(const i32x4*)(Al + aoff[kk][i]);
      #pragma unroll
      for (int j = 0; j < 4; ++j) bv[j] = *(const i32x4*)(Bl + boff[kk][j]);
      #pragma unroll
      for (int i = 0; i < 4; ++i)
        #pragma unroll
        for (int j = 0; j < 4; ++j)
          iacc[i][j] = __builtin_amdgcn_mfma_i32_16x16x64_i8(
              af[i], bv[j], iacc[i][j], 0, 0, 0);
    }
    cur ^= 1;
  }

  const int r4 = (lane >> 4) * 4;
  const int cn = lane & 15;
  float wo[4], qv[4][4];
  #pragma unroll
  for (int j = 0; j < 4; ++j) wo[j] = wsc[ocol0 + wc * 64 + j * 16 + cn];
  #pragma unroll
  for (int i = 0; i < 4; ++i)
    #pragma unroll
    for (int r = 0; r < 4; ++r)
      qv[i][r] = qs[srow0 + wr * 64 + i * 16 + r4 + r];

  f32x4 facc[4][4];
  #pragma unroll
  for (int i = 0; i < 4; ++i)
    #pragma unroll
    for (int j = 0; j < 4; ++j)
      #pragma unroll
      for (int r = 0; r < 4; ++r)
        facc[i][j][r] = (float)iacc[i][j][r] * wo[j] * qv[i][r];

  constexpr int NTF = (FPD * 2) / 128;   // 4
  for (int t = 0; t < NTF; ++t) {
    __syncthreads();
    if (t + 1 < NTF) stagefp((t + 1) * 128, cur ^ 1);
    const char* Al = &lds[cur][0][0][0];
    const char* Bl = &lds[cur][1][0][0];
    #pragma unroll
    for (int kk = 0; kk < 2; ++kk) {
      bf16x8 af[4], bv[4];
      #pragma unroll
      for (int i = 0; i < 4; ++i) af[i] = *(const bf16x8*)(Al + aoff[kk][i]);
      #pragma unroll
      for (int j = 0; j < 4; ++j) bv[j] = *(const bf16x8*)(Bl + boff[kk][j]);
      #pragma unroll
      for (int i = 0; i < 4; ++i)
        #pragma unroll
        for (int j = 0; j < 4; ++j)
          facc[i][j] = __builtin_amdgcn_mfma_f32_16x16x32_bf16(
              af[i], bv[j], facc[i][j], 0, 0, 0);
    }
    cur ^= 1;
  }

  #pragma unroll
  for (int j = 0; j < 4; ++j) {
    const int o  = ocol0 + wc * 64 + j * 16 + cn;
    const float bo = bias[o];
    #pragma unroll
    for (int i = 0; i < 4; ++i) {
      const int sbase = srow0 + wr * 64 + i * 16 + r4;
      #pragma unroll
      for (int r = 0; r < 4; ++r)
        out[(size_t)(sbase + r) * ODIM + o] = facc[i][j][r] + bo;
    }
  }
}

// ---------------------------------------------------------------------------
extern "C" void kernel_launch(void* const* d_in, const int* in_sizes, int n_in,
                              void* d_out, int out_size, void* d_ws, size_t ws_size,
                              hipStream_t stream) {
  const float* x    = (const float*)d_in[0];
  const float* iw   = (const float*)d_in[1];
  const float* fw   = (const float*)d_in[2];
  const float* wsc  = (const float*)d_in[3];
  const float* bias = (const float*)d_in[4];
  const int* int_idx = (const int*)d_in[5];
  const int* fp_idx  = (const int*)d_in[6];
  float* out = (float*)d_out;

  char* ws = (char*)d_ws;
  char* A8  = ws;                                   // 2048*3840  = 7.86 MB
  char* W8  = A8 + (size_t)SDIM * INTD;             // 4096*3840  = 15.7 MB
  char* Afp = W8 + (size_t)ODIM * INTD;             // 2048*256*2 = 1.0 MB
  char* Wfp = Afp + (size_t)SDIM * FPD * 2;         // 4096*256*2 = 2.1 MB
  float* qs = (float*)(Wfp + (size_t)ODIM * FPD * 2);

  prep_kernel<<<SDIM + ODIM, 256, 0, stream>>>(x, iw, fw, int_idx, fp_idx,
                                               (unsigned*)A8, (unsigned short*)Afp,
                                               (unsigned*)W8, (unsigned short*)Wfp, qs);
  gemm_kernel<<<512, 256, 0, stream>>>(A8, W8, Afp, Wfp, qs, wsc, bias, out);
}